// Round 1
// baseline (244.847 us; speedup 1.0000x reference)
//
#include <hip/hip_runtime.h>

typedef __bf16 bf16x8 __attribute__((ext_vector_type(8)));
typedef __bf16 bf16x4 __attribute__((ext_vector_type(4)));
typedef float f32x4 __attribute__((ext_vector_type(4)));

#define EPS_F 1e-5f

// -------------------------------------------------------------------------
// Kernel 1 (MFMA): pooled_part[mc][b][r] = (1/196) * sum_{p in m-chunk mc}
//                  hardswish(BN(sum_c x[b][c][p]*w1[r][c]))
// grid (128 b, 4 r-chunks of 64, 2 m-chunks of 112), block 512 (8 waves).
// M=112(pad112) x N=64 x K=1024, BK=32, mfma_f32_16x16x32_bf16.
// Round 6 change: M-split 224->112 doubles grid to 1024 blocks ->
// 4 blocks/CU (was grid-capped at 2, Occupancy 45%); f2bf bit-twiddle ->
// native __bf16 casts (compiler emits v_cvt_pk_bf16_f32, same RNE).
// Pool contributions are partial per m-chunk; k_logits sums the two parts.
// -------------------------------------------------------------------------
__global__ __launch_bounds__(512, 8) void k_gemm_pool(
    const float* __restrict__ x,
    const float* __restrict__ w1,
    const float* __restrict__ g1,
    const float* __restrict__ b1,
    const float* __restrict__ m1,
    const float* __restrict__ v1,
    float* __restrict__ pooled_part)     // [2][128][256]
{
    constexpr int LDK = 40;                  // padded k-stride (bf16)
    __shared__ __bf16 Alds[112 * LDK];       // [m=p][k]  8.75 KiB
    __shared__ __bf16 Blds[64 * LDK];        // [n=r][k]  5 KiB
    __shared__ float pool_lds[2][64];

    const int b   = blockIdx.x;
    const int r0  = blockIdx.y * 64;
    const int mc  = blockIdx.z;              // m-chunk: p in [mc*112, mc*112+112)
    const int tid = threadIdx.x;
    const int wave = tid >> 6, lane = tid & 63;
    const int wm = wave >> 2, wn = wave & 3; // wave grid 2(m) x 4(n)
    const int q  = lane >> 4, ln = lane & 15;
    const int nm = (wm == 0) ? 4 : 3;        // 7 m-tiles split 4 + 3

    f32x4 acc[4];
#pragma unroll
    for (int i = 0; i < 4; i++) acc[i] = (f32x4){0.f, 0.f, 0.f, 0.f};

    // A-staging unit: 4 c x 4 p.  224 active threads (28 p-units x 8 c-units)
    const int c4  = tid & 7;                 // c-group (4 channels)
    const int p4  = tid >> 3;                // p-group (4 positions), active < 28
    const bool a_act = (p4 < 28);
    const int  pg    = mc * 28 + p4;         // global p-group
    const bool a_val = a_act && (pg < 49);   // pg>=49 -> p>=196 -> zero rows
    const float* xb = x + (size_t)b * 1024 * 196 + pg * 4;

    const int rB = tid >> 3, k16 = tid & 7;  // B stage helpers (tid<512)

    for (int kc = 0; kc < 1024; kc += 32) {
        __syncthreads();
        // ---- stage B: w1 rows k-contiguous fp32, cvt -> bf16 ----
        {
            // 64 r x 8 k4-groups: thread covers 4 k
            const float4 f = *(const float4*)(w1 + (size_t)(r0 + rB) * 1024 + kc + k16 * 4);
            bf16x4 o = {(__bf16)f.x, (__bf16)f.y, (__bf16)f.z, (__bf16)f.w};
            *(bf16x4*)&Blds[rB * LDK + k16 * 4] = o;
        }
        // ---- stage A: fp32 [c][p] -> bf16 [p][c] (4x4 register transpose) ----
        if (a_act) {
            float fv[4][4];
            if (a_val) {
#pragma unroll
                for (int i = 0; i < 4; i++) {
                    const float4 f = *(const float4*)(xb + (size_t)(kc + c4 * 4 + i) * 196);
                    fv[i][0] = f.x; fv[i][1] = f.y; fv[i][2] = f.z; fv[i][3] = f.w;
                }
            } else {
#pragma unroll
                for (int i = 0; i < 4; i++)
#pragma unroll
                    for (int j = 0; j < 4; j++) fv[i][j] = 0.f;
            }
#pragma unroll
            for (int j = 0; j < 4; j++) {
                bf16x4 o = {(__bf16)fv[0][j], (__bf16)fv[1][j],
                            (__bf16)fv[2][j], (__bf16)fv[3][j]};
                *(bf16x4*)&Alds[(p4 * 4 + j) * LDK + c4 * 4] = o;  // 8B aligned
            }
        }
        __syncthreads();
        // ---- MFMA: 4 (wm=0) / 3 (wm=1) m-tiles x 1 n-tile per wave ----
        const bf16x8 bfr = *(const bf16x8*)&Blds[(wn * 16 + ln) * LDK + q * 8];
#pragma unroll
        for (int mi = 0; mi < 4; mi++) {
            if (mi < nm) {
                const int mt = wm * 4 + mi;
                const bf16x8 af = *(const bf16x8*)&Alds[(mt * 16 + ln) * LDK + q * 8];
                acc[mi] = __builtin_amdgcn_mfma_f32_16x16x32_bf16(af, bfr, acc[mi], 0, 0, 0);
            }
        }
    }

    // ---- epilogue: BN + hardswish + partial pool (mask p >= 196) ----
    float psum = 0.f;
    {
        const int r = r0 + wn * 16 + ln;
        const float s1 = g1[r] * rsqrtf(v1[r] + EPS_F);
        const float mu = m1[r];
        const float be = b1[r];
#pragma unroll
        for (int mi = 0; mi < 4; mi++) {
            if (mi < nm) {
                const int mt = wm * 4 + mi;
#pragma unroll
                for (int i = 0; i < 4; i++) {
                    const int m = mc * 112 + mt * 16 + q * 4 + i; // C/D: row=(lane>>4)*4+i
                    if (m < 196) {
                        float v = acc[mi][i];
                        v = (v - mu) * s1 + be;
                        const float g = fminf(fmaxf(v + 3.f, 0.f), 6.f);
                        psum += v * g * (1.f / 6.f);
                    }
                }
            }
        }
    }
    psum += __shfl_xor(psum, 16, 64);
    psum += __shfl_xor(psum, 32, 64);
    if (lane < 16) pool_lds[wm][wn * 16 + lane] = psum;
    __syncthreads();
    if (tid < 64)
        pooled_part[(size_t)mc * (128 * 256) + b * 256 + r0 + tid] =
            (pool_lds[0][tid] + pool_lds[1][tid]) * (1.f / 196.f);
}

// -------------------------------------------------------------------------
// Kernel 2: logits = (part0+part1) @ w2^T; BN2; sigmoid -> roi [128][6] f32
// grid 128, block 64.
// -------------------------------------------------------------------------
__global__ __launch_bounds__(64) void k_logits(
    const float* __restrict__ pooled_part,   // [2][128][256]
    const float* __restrict__ w2,
    const float* __restrict__ g2,
    const float* __restrict__ b2,
    const float* __restrict__ m2,
    const float* __restrict__ v2,
    float* __restrict__ roi)
{
    const int b = blockIdx.x, t = threadIdx.x;
    const float4 pa = ((const float4*)(pooled_part + b * 256))[t];
    const float4 pb = ((const float4*)(pooled_part + 128 * 256 + b * 256))[t];
    float4 p4;
    p4.x = pa.x + pb.x; p4.y = pa.y + pb.y;
    p4.z = pa.z + pb.z; p4.w = pa.w + pb.w;
    float part[6];
#pragma unroll
    for (int j = 0; j < 6; j++) {
        const float4 w = *(const float4*)(w2 + j * 256 + t * 4);
        part[j] = p4.x * w.x + p4.y * w.y + p4.z * w.z + p4.w * w.w;
    }
#pragma unroll
    for (int j = 0; j < 6; j++)
#pragma unroll
        for (int off = 32; off >= 1; off >>= 1)
            part[j] += __shfl_xor(part[j], off, 64);
    if (t == 0) {
        const float SC[3] = {7.f, 7.f, 4.f};
        float raw[6];
#pragma unroll
        for (int j = 0; j < 6; j++) {
            float l = part[j];
            const float s = g2[j] * rsqrtf(v2[j] + EPS_F);
            l = (l - m2[j]) * s + b2[j];
            raw[j] = 1.f / (1.f + expf(-l));
        }
#pragma unroll
        for (int d = 0; d < 3; d++) {
            roi[b * 6 + d]     = 0.5f * raw[d] * SC[d];             // start (x,y,t)
            roi[b * 6 + 3 + d] = (1.f - 0.5f * raw[3 + d]) * SC[d]; // end
        }
    }
}

__device__ __forceinline__ void prep1(float s, float e, int n, int size, int i,
                                      int& lo, int& hi, float& w0, float& w1)
{
    const float bsz = (e - s) / (float)n;
    float c = s + ((float)i + 0.5f) * bsz;
    const float valid = (c >= -1.f && c <= (float)size) ? 1.f : 0.f;
    c = fminf(fmaxf(c, 0.f), (float)(size - 1));
    lo = (int)floorf(c);
    hi = min(lo + 1, size - 1);
    const float f = c - (float)lo;
    w0 = (1.f - f) * valid;
    w1 = f * valid;
}

// -------------------------------------------------------------------------
// Kernel 3: ROI-align 3D. Block = (b, 32 channels): stage channels in LDS,
// precompute 75x8 (offset, weight) tables (transposed [8][80] -> conflict-
// free reads), then 8 LDS-FMA per output. grid (128, 32), block 256.
// -------------------------------------------------------------------------
__global__ __launch_bounds__(256) void k_roi(
    const float* __restrict__ x,
    const float* __restrict__ roi,
    float* __restrict__ out)
{
    __shared__ float xs[32 * 200];   // 32 ch x 196 (pad 200)  25.6 KiB
    __shared__ int   soff[8][80];    // sample flat offsets (po-major)
    __shared__ float swt[8][80];     // sample weights

    const int b = blockIdx.x, c0 = blockIdx.y * 32;
    const int tid = threadIdx.x;

    // ---- stage 32 channels, coalesced float4 (196 = 49*4) ----
    const float* xb = x + ((size_t)b * 1024 + c0) * 196;
#pragma unroll
    for (int k = 0; k < 7; k++) {
        const int i4 = tid + k * 256;
        if (i4 < 1568) {                       // 32*49
            const int c = i4 / 49, pq = i4 % 49;
            const float4 v = *(const float4*)(xb + c * 196 + pq * 4);
            *(float4*)&xs[c * 200 + pq * 4] = v;
        }
    }
    // ---- weight/offset tables (75 threads) ----
    if (tid < 75) {
        const int po = tid;
        const int to = po / 25, rem = po % 25, yo = rem / 5, xo = rem % 5;
        const float sx = roi[b * 6 + 0], ex = roi[b * 6 + 3];
        const float sy = roi[b * 6 + 1], ey = roi[b * 6 + 4];
        const float st = roi[b * 6 + 2], et = roi[b * 6 + 5];
        int tl, th, yl, yh, xl, xh;
        float tw0, tw1, yw0, yw1, xw0, xw1;
        prep1(st, et, 3, 4, to, tl, th, tw0, tw1);
        prep1(sy, ey, 5, 7, yo, yl, yh, yw0, yw1);
        prep1(sx, ex, 5, 7, xo, xl, xh, xw0, xw1);
#pragma unroll
        for (int s = 0; s < 8; s++) {
            const int   ti = (s & 4) ? th : tl;
            const int   yi = (s & 2) ? yh : yl;
            const int   xi = (s & 1) ? xh : xl;
            const float w = ((s & 4) ? tw1 : tw0) *
                            ((s & 2) ? yw1 : yw0) *
                            ((s & 1) ? xw1 : xw0);
            soff[s][po] = ti * 49 + yi * 7 + xi;
            swt[s][po]  = w;
        }
    }
    __syncthreads();

    // ---- compute: 32*75 = 2400 outputs ----
    const size_t obase = ((size_t)b * 1024 + c0) * 75;
#pragma unroll
    for (int k = 0; k < 10; k++) {
        const int e = tid + k * 256;
        if (e < 2400) {
            const int c = e / 75, po = e % 75;
            const float* row = &xs[c * 200];
            float v = 0.f;
#pragma unroll
            for (int s = 0; s < 8; s++)
                v += swt[s][po] * row[soff[s][po]];
            out[obase + e] = v;     // e == c*75+po: fully coalesced
        }
    }
}

extern "C" void kernel_launch(void* const* d_in, const int* in_sizes, int n_in,
                              void* d_out, int out_size, void* d_ws, size_t ws_size,
                              hipStream_t stream)
{
    const float* x  = (const float*)d_in[0];
    const float* w1 = (const float*)d_in[1];
    const float* g1 = (const float*)d_in[2];
    const float* b1 = (const float*)d_in[3];
    const float* m1 = (const float*)d_in[4];
    const float* v1 = (const float*)d_in[5];
    const float* w2 = (const float*)d_in[6];
    const float* g2 = (const float*)d_in[7];
    const float* b2 = (const float*)d_in[8];
    const float* m2 = (const float*)d_in[9];
    const float* v2 = (const float*)d_in[10];

    float* pooled_part = (float*)d_ws;               // 2*128*256 f32 (512 KB incl. roi)
    float* roi         = pooled_part + 2 * 128 * 256;
    float* out         = (float*)d_out;

    k_gemm_pool<<<dim3(128, 4, 2), 512, 0, stream>>>(x, w1, g1, b1, m1, v1, pooled_part);
    k_logits<<<128, 64, 0, stream>>>(pooled_part, w2, g2, b2, m2, v2, roi);
    k_roi<<<dim3(128, 32), 256, 0, stream>>>(x, roi, out);
}

// Round 2
// 241.597 us; speedup vs baseline: 1.0134x; 1.0134x over previous
//
#include <hip/hip_runtime.h>

typedef __bf16 bf16x8 __attribute__((ext_vector_type(8)));
typedef __bf16 bf16x4 __attribute__((ext_vector_type(4)));
typedef float f32x4 __attribute__((ext_vector_type(4)));

#define EPS_F 1e-5f

// -------------------------------------------------------------------------
// Kernel 1 (MFMA): pooled_part[mc][b][r] = sum_{p in m-chunk} hswish(BN(x@w1))
// Round 7: kill the 4x redundant x reads (L3-BW bound, ~737 MB demand).
// Each block now computes the FULL N=256: grid (128 b, 2 mc) = 256 blocks,
// block 512 (8 waves: 2m x 4n), per wave 4(3) m-tiles x 4 n-tiles.
// Demand: x 469->117 MB (L3), w1 268 MB but L2-resident (1 MB).
// Register-prefetch of next K-step hides global latency at 1 block/CU.
// M=112 x N=256 x K=1024, BK=32, mfma_f32_16x16x32_bf16.
// -------------------------------------------------------------------------
__global__ __launch_bounds__(512) void k_gemm_pool(
    const float* __restrict__ x,
    const float* __restrict__ w1,
    const float* __restrict__ g1,
    const float* __restrict__ b1,
    const float* __restrict__ m1,
    const float* __restrict__ v1,
    float* __restrict__ pooled_part)     // [2][128][256]
{
    constexpr int LDK = 40;                  // padded k-stride (bf16)
    __shared__ __bf16 Alds[112 * LDK];       // [m=p][k]   8.75 KiB
    __shared__ __bf16 Blds[256 * LDK];       // [n=r][k]  20 KiB
    __shared__ float pool_lds[2][256];       //            2 KiB

    const int b   = blockIdx.x;
    const int mc  = blockIdx.y;              // m-chunk: p in [mc*112, mc*112+112)
    const int tid = threadIdx.x;
    const int wave = tid >> 6, lane = tid & 63;
    const int wm = wave >> 2, wn = wave & 3; // wave grid 2(m) x 4(n)
    const int q  = lane >> 4, ln = lane & 15;
    const int nm = (wm == 0) ? 4 : 3;        // 7 m-tiles split 4 + 3

    f32x4 acc[4][4];                         // [mi][ni]
#pragma unroll
    for (int i = 0; i < 4; i++)
#pragma unroll
        for (int j = 0; j < 4; j++) acc[i][j] = (f32x4){0.f, 0.f, 0.f, 0.f};

    // A-staging unit: 4 c x 4 p.  224 active threads (28 p-units x 8 c-units)
    const int c4  = tid & 7;                 // c-group (4 channels)
    const int p4  = tid >> 3;                // p-group (4 positions), active < 28
    const bool a_act = (p4 < 28);
    const int  pg    = mc * 28 + p4;         // global p-group
    const bool a_val = a_act && (pg < 49);   // pg>=49 -> p>=196 -> zero rows
    const float* xb = x + (size_t)b * (1024 * 196) + pg * 4;

    // B-staging unit: row rB, half kh (16 k each); 512 threads cover 256rx32k
    const int rB = tid & 255, kh = tid >> 8;
    const float* wrow = w1 + (size_t)rB * 1024 + kh * 16;

    float  fA[4][4];                          // [c][p] fp32 staging regs
    float4 fB[4];

    // ---- register prefetch helpers ----
    auto loadA = [&](int kc) {
        if (a_val) {
#pragma unroll
            for (int i = 0; i < 4; i++) {
                const float4 f = *(const float4*)(xb + (size_t)(kc + c4 * 4 + i) * 196);
                fA[i][0] = f.x; fA[i][1] = f.y; fA[i][2] = f.z; fA[i][3] = f.w;
            }
        } else {
#pragma unroll
            for (int i = 0; i < 4; i++)
#pragma unroll
                for (int j = 0; j < 4; j++) fA[i][j] = 0.f;
        }
    };
    auto loadB = [&](int kc) {
#pragma unroll
        for (int j = 0; j < 4; j++)
            fB[j] = *(const float4*)(wrow + kc + j * 4);
    };

    loadB(0);
    if (a_act) loadA(0);

    for (int kc = 0; kc < 1024; kc += 32) {
        __syncthreads();                     // prev iter's LDS reads done
        // ---- write staged regs -> LDS (cvt fp32->bf16 here) ----
        {
            bf16x8 lo = {(__bf16)fB[0].x, (__bf16)fB[0].y, (__bf16)fB[0].z, (__bf16)fB[0].w,
                         (__bf16)fB[1].x, (__bf16)fB[1].y, (__bf16)fB[1].z, (__bf16)fB[1].w};
            bf16x8 hi = {(__bf16)fB[2].x, (__bf16)fB[2].y, (__bf16)fB[2].z, (__bf16)fB[2].w,
                         (__bf16)fB[3].x, (__bf16)fB[3].y, (__bf16)fB[3].z, (__bf16)fB[3].w};
            *(bf16x8*)&Blds[rB * LDK + kh * 16]     = lo;   // byte = rB*80+kh*32, 16B aligned
            *(bf16x8*)&Blds[rB * LDK + kh * 16 + 8] = hi;
        }
        if (a_act) {
#pragma unroll
            for (int j = 0; j < 4; j++) {
                bf16x4 o = {(__bf16)fA[0][j], (__bf16)fA[1][j],
                            (__bf16)fA[2][j], (__bf16)fA[3][j]};
                *(bf16x4*)&Alds[(p4 * 4 + j) * LDK + c4 * 4] = o;  // 8B aligned
            }
        }
        // ---- prefetch next K-step while this one is consumed ----
        if (kc + 32 < 1024) {
            loadB(kc + 32);
            if (a_act) loadA(kc + 32);
        }
        __syncthreads();
        // ---- MFMA: 4(3) m-tiles x 4 n-tiles per wave ----
        bf16x8 bfr[4];
#pragma unroll
        for (int ni = 0; ni < 4; ni++)
            bfr[ni] = *(const bf16x8*)&Blds[((wn * 4 + ni) * 16 + ln) * LDK + q * 8];
#pragma unroll
        for (int mi = 0; mi < 4; mi++) {
            if (mi < nm) {
                const bf16x8 af = *(const bf16x8*)&Alds[((wm * 4 + mi) * 16 + ln) * LDK + q * 8];
#pragma unroll
                for (int ni = 0; ni < 4; ni++)
                    acc[mi][ni] = __builtin_amdgcn_mfma_f32_16x16x32_bf16(af, bfr[ni], acc[mi][ni], 0, 0, 0);
            }
        }
    }

    // ---- epilogue: BN + hardswish + partial pool (mask p >= 196) ----
    float psum[4] = {0.f, 0.f, 0.f, 0.f};
#pragma unroll
    for (int ni = 0; ni < 4; ni++) {
        const int r = (wn * 4 + ni) * 16 + ln;
        const float s1 = g1[r] * rsqrtf(v1[r] + EPS_F);
        const float mu = m1[r];
        const float be = b1[r];
#pragma unroll
        for (int mi = 0; mi < 4; mi++) {
            if (mi < nm) {
#pragma unroll
                for (int i = 0; i < 4; i++) {
                    const int m = mc * 112 + (wm * 4 + mi) * 16 + q * 4 + i;
                    if (m < 196) {
                        float v = acc[mi][ni][i];
                        v = (v - mu) * s1 + be;
                        const float g = fminf(fmaxf(v + 3.f, 0.f), 6.f);
                        psum[ni] += v * g * (1.f / 6.f);
                    }
                }
            }
        }
    }
#pragma unroll
    for (int ni = 0; ni < 4; ni++) {
        psum[ni] += __shfl_xor(psum[ni], 16, 64);
        psum[ni] += __shfl_xor(psum[ni], 32, 64);
    }
    if (lane < 16) {
#pragma unroll
        for (int ni = 0; ni < 4; ni++)
            pool_lds[wm][(wn * 4 + ni) * 16 + lane] = psum[ni];
    }
    __syncthreads();
    if (tid < 256)
        pooled_part[(size_t)mc * (128 * 256) + b * 256 + tid] =
            (pool_lds[0][tid] + pool_lds[1][tid]) * (1.f / 196.f);
}

// -------------------------------------------------------------------------
// Kernel 2: logits = (part0+part1) @ w2^T; BN2; sigmoid -> roi [128][6] f32
// grid 128, block 64.
// -------------------------------------------------------------------------
__global__ __launch_bounds__(64) void k_logits(
    const float* __restrict__ pooled_part,   // [2][128][256]
    const float* __restrict__ w2,
    const float* __restrict__ g2,
    const float* __restrict__ b2,
    const float* __restrict__ m2,
    const float* __restrict__ v2,
    float* __restrict__ roi)
{
    const int b = blockIdx.x, t = threadIdx.x;
    const float4 pa = ((const float4*)(pooled_part + b * 256))[t];
    const float4 pb = ((const float4*)(pooled_part + 128 * 256 + b * 256))[t];
    float4 p4;
    p4.x = pa.x + pb.x; p4.y = pa.y + pb.y;
    p4.z = pa.z + pb.z; p4.w = pa.w + pb.w;
    float part[6];
#pragma unroll
    for (int j = 0; j < 6; j++) {
        const float4 w = *(const float4*)(w2 + j * 256 + t * 4);
        part[j] = p4.x * w.x + p4.y * w.y + p4.z * w.z + p4.w * w.w;
    }
#pragma unroll
    for (int j = 0; j < 6; j++)
#pragma unroll
        for (int off = 32; off >= 1; off >>= 1)
            part[j] += __shfl_xor(part[j], off, 64);
    if (t == 0) {
        const float SC[3] = {7.f, 7.f, 4.f};
        float raw[6];
#pragma unroll
        for (int j = 0; j < 6; j++) {
            float l = part[j];
            const float s = g2[j] * rsqrtf(v2[j] + EPS_F);
            l = (l - m2[j]) * s + b2[j];
            raw[j] = 1.f / (1.f + expf(-l));
        }
#pragma unroll
        for (int d = 0; d < 3; d++) {
            roi[b * 6 + d]     = 0.5f * raw[d] * SC[d];             // start (x,y,t)
            roi[b * 6 + 3 + d] = (1.f - 0.5f * raw[3 + d]) * SC[d]; // end
        }
    }
}

__device__ __forceinline__ void prep1(float s, float e, int n, int size, int i,
                                      int& lo, int& hi, float& w0, float& w1)
{
    const float bsz = (e - s) / (float)n;
    float c = s + ((float)i + 0.5f) * bsz;
    const float valid = (c >= -1.f && c <= (float)size) ? 1.f : 0.f;
    c = fminf(fmaxf(c, 0.f), (float)(size - 1));
    lo = (int)floorf(c);
    hi = min(lo + 1, size - 1);
    const float f = c - (float)lo;
    w0 = (1.f - f) * valid;
    w1 = f * valid;
}

// -------------------------------------------------------------------------
// Kernel 3: ROI-align 3D. Block = (b, 32 channels): stage channels in LDS,
// precompute 75x8 (offset, weight) tables (transposed [8][80] -> conflict-
// free reads), then 8 LDS-FMA per output. grid (128, 32), block 256.
// -------------------------------------------------------------------------
__global__ __launch_bounds__(256) void k_roi(
    const float* __restrict__ x,
    const float* __restrict__ roi,
    float* __restrict__ out)
{
    __shared__ float xs[32 * 200];   // 32 ch x 196 (pad 200)  25.6 KiB
    __shared__ int   soff[8][80];    // sample flat offsets (po-major)
    __shared__ float swt[8][80];     // sample weights

    const int b = blockIdx.x, c0 = blockIdx.y * 32;
    const int tid = threadIdx.x;

    // ---- stage 32 channels, coalesced float4 (196 = 49*4) ----
    const float* xb = x + ((size_t)b * 1024 + c0) * 196;
#pragma unroll
    for (int k = 0; k < 7; k++) {
        const int i4 = tid + k * 256;
        if (i4 < 1568) {                       // 32*49
            const int c = i4 / 49, pq = i4 % 49;
            const float4 v = *(const float4*)(xb + c * 196 + pq * 4);
            *(float4*)&xs[c * 200 + pq * 4] = v;
        }
    }
    // ---- weight/offset tables (75 threads) ----
    if (tid < 75) {
        const int po = tid;
        const int to = po / 25, rem = po % 25, yo = rem / 5, xo = rem % 5;
        const float sx = roi[b * 6 + 0], ex = roi[b * 6 + 3];
        const float sy = roi[b * 6 + 1], ey = roi[b * 6 + 4];
        const float st = roi[b * 6 + 2], et = roi[b * 6 + 5];
        int tl, th, yl, yh, xl, xh;
        float tw0, tw1, yw0, yw1, xw0, xw1;
        prep1(st, et, 3, 4, to, tl, th, tw0, tw1);
        prep1(sy, ey, 5, 7, yo, yl, yh, yw0, yw1);
        prep1(sx, ex, 5, 7, xo, xl, xh, xw0, xw1);
#pragma unroll
        for (int s = 0; s < 8; s++) {
            const int   ti = (s & 4) ? th : tl;
            const int   yi = (s & 2) ? yh : yl;
            const int   xi = (s & 1) ? xh : xl;
            const float w = ((s & 4) ? tw1 : tw0) *
                            ((s & 2) ? yw1 : yw0) *
                            ((s & 1) ? xw1 : xw0);
            soff[s][po] = ti * 49 + yi * 7 + xi;
            swt[s][po]  = w;
        }
    }
    __syncthreads();

    // ---- compute: 32*75 = 2400 outputs ----
    const size_t obase = ((size_t)b * 1024 + c0) * 75;
#pragma unroll
    for (int k = 0; k < 10; k++) {
        const int e = tid + k * 256;
        if (e < 2400) {
            const int c = e / 75, po = e % 75;
            const float* row = &xs[c * 200];
            float v = 0.f;
#pragma unroll
            for (int s = 0; s < 8; s++)
                v += swt[s][po] * row[soff[s][po]];
            out[obase + e] = v;     // e == c*75+po: fully coalesced
        }
    }
}

extern "C" void kernel_launch(void* const* d_in, const int* in_sizes, int n_in,
                              void* d_out, int out_size, void* d_ws, size_t ws_size,
                              hipStream_t stream)
{
    const float* x  = (const float*)d_in[0];
    const float* w1 = (const float*)d_in[1];
    const float* g1 = (const float*)d_in[2];
    const float* b1 = (const float*)d_in[3];
    const float* m1 = (const float*)d_in[4];
    const float* v1 = (const float*)d_in[5];
    const float* w2 = (const float*)d_in[6];
    const float* g2 = (const float*)d_in[7];
    const float* b2 = (const float*)d_in[8];
    const float* m2 = (const float*)d_in[9];
    const float* v2 = (const float*)d_in[10];

    float* pooled_part = (float*)d_ws;               // 2*128*256 f32
    float* roi         = pooled_part + 2 * 128 * 256;
    float* out         = (float*)d_out;

    k_gemm_pool<<<dim3(128, 2), 512, 0, stream>>>(x, w1, g1, b1, m1, v1, pooled_part);
    k_logits<<<128, 64, 0, stream>>>(pooled_part, w2, g2, b2, m2, v2, roi);
    k_roi<<<dim3(128, 32), 256, 0, stream>>>(x, roi, out);
}